// Round 12
// baseline (363.812 us; speedup 1.0000x reference)
//
#include <hip/hip_runtime.h>
#include <math.h>

// WinGNN forward on MI355X — f32 throughout (no fp32 MFMA on CDNA4).
//
// Pipeline (all on `stream`, graph-capture safe):
//  1. k_init        : deg=1 (self-loop), indeg=0
//  2. k_count       : atomic degree counts by row (norm) and col (CSR build)
//  3. k_blocksum    : per-256-chunk sum of indeg -> bsum ; dinv=rsqrt(deg)
//     k_scan_bsums  : 1-block exclusive scan of 196 bsums -> boff
//     k_colptr      : per-chunk LDS scan + boff -> colptr/cursor
//  4. k_fill        : CSR fill (csrc[pos] = row[e]) via atomic cursor
//  5. k_transW      : WT1[k][n]=W1[n][k]; WTl1[k][n]=Wl1 concat-transposed
//  6. k_gemm2<128,64,1> : h = relu(x @ W1^T + b1)   [LDS-broadcast A, coalesced W/C]
//  7. k_agg<0>      : hn = A(h);  hidden = h + hn   [shuffle-broadcast gather]
//     k_agg<1>      : hidden += A(hn); fused row-L2-normalize
//  8. k_gemm2<256,32,0> : Z[v][n] = hid @ WTl1
//  9. k_edge        : pred[e] = b_l2 + sum_o Wl2[o]*relu(bl1[o]+Z[i][o]+Z[j][128+o])

#define NN 50000
#define NE 500000
#define NL 100000
#define NB 196  // ceil(NN/256)

__global__ __launch_bounds__(256) void k_init(int* __restrict__ deg,
                                              int* __restrict__ indeg) {
  int i = blockIdx.x * 256 + threadIdx.x;
  if (i < NN) { deg[i] = 1; indeg[i] = 0; }
}

__global__ __launch_bounds__(256) void k_count(const int* __restrict__ ei,
                                               int* __restrict__ deg,
                                               int* __restrict__ indeg) {
  int e = blockIdx.x * 256 + threadIdx.x;
  if (e < NE) {
    atomicAdd(&deg[ei[e]], 1);        // row -> deg (normalization)
    atomicAdd(&indeg[ei[NE + e]], 1); // col -> indeg (CSR)
  }
}

// ---- hierarchical scan stage 1: block sums (coalesced) + dinv ----
__global__ __launch_bounds__(256) void k_blocksum(const int* __restrict__ indeg,
                                                  const int* __restrict__ deg,
                                                  float* __restrict__ dinv,
                                                  int* __restrict__ bsum) {
  __shared__ int red[4];
  int t = threadIdx.x;
  int i = blockIdx.x * 256 + t;
  int v = (i < NN) ? indeg[i] : 0;
  if (i < NN) dinv[i] = 1.0f / sqrtf((float)deg[i]);  // deg >= 1 (self loop)
  int sum = v;
#pragma unroll
  for (int d = 1; d < 64; d <<= 1) sum += __shfl_xor(sum, d, 64);
  if ((t & 63) == 0) red[t >> 6] = sum;
  __syncthreads();
  if (t == 0) bsum[blockIdx.x] = red[0] + red[1] + red[2] + red[3];
}

// ---- stage 2: exclusive scan of NB block sums (single tiny block) ----
__global__ __launch_bounds__(256) void k_scan_bsums(const int* __restrict__ bsum,
                                                    int* __restrict__ boff) {
  __shared__ int s[256];
  int t = threadIdx.x;
  int v = (t < NB) ? bsum[t] : 0;
  s[t] = v;
  __syncthreads();
  for (int d = 1; d < 256; d <<= 1) {
    int u = (t >= d) ? s[t - d] : 0;
    __syncthreads();
    s[t] += u;
    __syncthreads();
  }
  if (t < NB) boff[t] = s[t] - v;  // exclusive prefix
}

// ---- stage 3: per-block scan + offset -> colptr/cursor (coalesced) ----
__global__ __launch_bounds__(256) void k_colptr(const int* __restrict__ indeg,
                                                const int* __restrict__ boff,
                                                int* __restrict__ colptr,
                                                int* __restrict__ cursor) {
  __shared__ int s[256];
  int t = threadIdx.x;
  int i = blockIdx.x * 256 + t;
  int v = (i < NN) ? indeg[i] : 0;
  s[t] = v;
  __syncthreads();
  for (int d = 1; d < 256; d <<= 1) {
    int u = (t >= d) ? s[t - d] : 0;
    __syncthreads();
    s[t] += u;
    __syncthreads();
  }
  int incl = s[t];
  int base = boff[blockIdx.x];
  if (i < NN) {
    int ex = base + incl - v;
    colptr[i] = ex;
    cursor[i] = ex;
    if (i == NN - 1) colptr[NN] = base + incl;  // == NE
  }
}

__global__ __launch_bounds__(256) void k_fill(const int* __restrict__ ei,
                                              int* __restrict__ cursor,
                                              int* __restrict__ csrc) {
  int e = blockIdx.x * 256 + threadIdx.x;
  if (e < NE) {
    int c = ei[NE + e];
    int pos = atomicAdd(&cursor[c], 1);
    csrc[pos] = ei[e];
  }
}

// ---- weight transpose (one-time, ~192KB): WT[k][n] layouts ----
// WT1 [128][128]: WT1[k*128+n]  = W1[n*128+k]
// WTl1[128][256]: WTl1[k*256+n] = (n<128) ? Wl1[n*256+k] : Wl1[(n-128)*256+128+k]
__global__ __launch_bounds__(256) void k_transW(const float* __restrict__ W1,
                                                const float* __restrict__ Wl1,
                                                float* __restrict__ WT1,
                                                float* __restrict__ WTl1) {
  int i = blockIdx.x * 256 + threadIdx.x;
  if (i < 128 * 128) {
    int k = i >> 7, n = i & 127;
    WT1[i] = W1[n * 128 + k];
  } else {
    int i2 = i - 128 * 128;
    if (i2 < 128 * 256) {
      int k = i2 >> 8, n = i2 & 255;
      WTl1[i2] = (n < 128) ? Wl1[n * 256 + k] : Wl1[(n - 128) * 256 + 128 + k];
    }
  }
}

// ---------------- GEMM2: C[M x NCOL] = act(A[M x 128] @ WT (+ bias)) --------
// Block 256 thr (4 waves), tile TM rows. A-tile staged flat (coalesced) into
// LDS; compute: each HALF-WAVE owns 8 rows x 128 cols (lane&31 -> 4 cols via
// float4). A comes from ds_read_b128 at a half-wave-uniform address ->
// broadcast, 2 distinct addrs/wave = free. W loads and C stores coalesced.
// NCOL=128: TM=64 (CG=1, bias+relu). NCOL=256: TM=32 (CG=2 col-split).
template <int NCOL, int TM, int RELU>
__global__ __launch_bounds__(256) void k_gemm2(const float* __restrict__ A,
                                               const float* __restrict__ WT,
                                               const float* __restrict__ bias,
                                               float* __restrict__ C) {
  __shared__ float As[TM * 128];
  int t = threadIdx.x;
  int m0 = blockIdx.x * TM;
  // flat coalesced staging (contiguous 16B chunks, lanes sweep addresses)
  for (int i = t * 4; i < TM * 128; i += 1024) {
    int row = m0 + (i >> 7);
    float4 v = (row < NN) ? *(const float4*)(A + (size_t)m0 * 128 + i)
                          : make_float4(0.f, 0.f, 0.f, 0.f);
    *(float4*)&As[i] = v;
  }
  __syncthreads();

  constexpr int CG = NCOL / 128;       // col groups per block
  int lane = t & 63, w = t >> 6;
  int colbase = (w % CG) * 128;
  int g = w / CG;
  int half = lane >> 5;
  int rbase = (g * 2 + half) * 8;      // 8 rows per half-wave
  int c0 = colbase + (lane & 31) * 4;  // 4 cols per lane, half covers 128

  float4 acc[8];
#pragma unroll
  for (int r = 0; r < 8; ++r) acc[r] = make_float4(0.f, 0.f, 0.f, 0.f);

  for (int k0 = 0; k0 < 128; k0 += 4) {
    float4 a4[8];
#pragma unroll
    for (int r = 0; r < 8; ++r)
      a4[r] = *(const float4*)&As[(rbase + r) * 128 + k0];  // LDS broadcast
#pragma unroll
    for (int kk = 0; kk < 4; ++kk) {
      float4 wv = *(const float4*)(WT + (size_t)(k0 + kk) * NCOL + c0);  // coalesced
#pragma unroll
      for (int r = 0; r < 8; ++r) {
        float ar = (kk == 0) ? a4[r].x : (kk == 1) ? a4[r].y
                 : (kk == 2) ? a4[r].z : a4[r].w;
        acc[r].x += ar * wv.x;
        acc[r].y += ar * wv.y;
        acc[r].z += ar * wv.z;
        acc[r].w += ar * wv.w;
      }
    }
  }

#pragma unroll
  for (int r = 0; r < 8; ++r) {
    int m = m0 + rbase + r;
    if (m < NN) {
      float4 o = acc[r];
      if (RELU) {
        float4 bb = *(const float4*)(bias + c0);
        o.x = fmaxf(o.x + bb.x, 0.f);
        o.y = fmaxf(o.y + bb.y, 0.f);
        o.z = fmaxf(o.z + bb.z, 0.f);
        o.w = fmaxf(o.w + bb.w, 0.f);
      }
      *(float4*)(C + (size_t)m * NCOL + c0) = o;  // coalesced
    }
  }
}

// ---------------- aggregation hop ----------------
// half-wave (32 lanes x float4) per node:
// agg = dinv[v] * ( sum_in dinv[src]*in[src] + dinv[v]*in[v] )
// Edge indices + dinv prefetched 32-at-a-time cooperatively (coalesced) and
// broadcast via width-32 shuffles; feature gathers 2-way unrolled.
// LAST=0: out = agg; hidden = in[v] + agg
// LAST=1: hidden += agg, then fused row-L2-normalize (no out store)
template <int LAST>
__global__ __launch_bounds__(256) void k_agg(const float* __restrict__ in,
                                             float* __restrict__ out,
                                             float* __restrict__ hidden,
                                             const float* __restrict__ dinv,
                                             const int* __restrict__ colptr,
                                             const int* __restrict__ csrc) {
  int v = (blockIdx.x * 256 + threadIdx.x) >> 5;
  int l = threadIdx.x & 31;
  if (v >= NN) return;
  float dv = dinv[v];
  float4 sv = *(const float4*)(in + (size_t)v * 128 + l * 4);
  float ax = sv.x * dv, ay = sv.y * dv, az = sv.z * dv, aw = sv.w * dv;
  int s = colptr[v], e = colptr[v + 1];
  for (int p0 = s; p0 < e; p0 += 32) {
    int cnt = e - p0;
    if (cnt > 32) cnt = 32;
    int myi = (l < cnt) ? csrc[p0 + l] : 0;     // coalesced 128B index load
    float myd = (l < cnt) ? dinv[myi] : 0.0f;   // one dinv gather per edge
    int q = 0;
    for (; q + 1 < cnt; q += 2) {
      int s0 = __shfl(myi, q, 32);
      int s1 = __shfl(myi, q + 1, 32);
      float d0 = __shfl(myd, q, 32);
      float d1 = __shfl(myd, q + 1, 32);
      float4 h0 = *(const float4*)(in + (size_t)s0 * 128 + l * 4);
      float4 h1 = *(const float4*)(in + (size_t)s1 * 128 + l * 4);
      ax += h0.x * d0 + h1.x * d1;
      ay += h0.y * d0 + h1.y * d1;
      az += h0.z * d0 + h1.z * d1;
      aw += h0.w * d0 + h1.w * d1;
    }
    if (q < cnt) {
      int s0 = __shfl(myi, q, 32);
      float d0 = __shfl(myd, q, 32);
      float4 h0 = *(const float4*)(in + (size_t)s0 * 128 + l * 4);
      ax += h0.x * d0;
      ay += h0.y * d0;
      az += h0.z * d0;
      aw += h0.w * d0;
    }
  }
  ax *= dv; ay *= dv; az *= dv; aw *= dv;
  if (!LAST) {
    float4 o4 = {ax, ay, az, aw};
    *(float4*)(out + (size_t)v * 128 + l * 4) = o4;
    float4 hd = {sv.x + ax, sv.y + ay, sv.z + az, sv.w + aw};
    *(float4*)(hidden + (size_t)v * 128 + l * 4) = hd;
  } else {
    float4 hp = *(const float4*)(hidden + (size_t)v * 128 + l * 4);
    float4 hd = {hp.x + ax, hp.y + ay, hp.z + az, hp.w + aw};
    // fused F.normalize: half-wave owns the whole 128-dim row
    float ss = hd.x * hd.x + hd.y * hd.y + hd.z * hd.z + hd.w * hd.w;
#pragma unroll
    for (int d = 1; d < 32; d <<= 1) ss += __shfl_xor(ss, d, 64);  // masks 1..16
    float sc = 1.0f / fmaxf(sqrtf(ss), 1e-12f);
    float4 r = {hd.x * sc, hd.y * sc, hd.z * sc, hd.w * sc};
    *(float4*)(hidden + (size_t)v * 128 + l * 4) = r;
  }
}

// ---------------- edge head reduce ----------------
// 16 lanes per edge, each lane covers o = l*4..+3 and o = 64+l*4..+3:
// pred[e] = b_l2 + sum_{o<128} Wl2[o]*relu(bl1[o]+Z[i][o]+Z[j][128+o])
__global__ __launch_bounds__(256) void k_edge(const float* __restrict__ Z,
                                              const float* __restrict__ bl1,
                                              const float* __restrict__ Wl2,
                                              const float* __restrict__ bl2,
                                              const int* __restrict__ eli,
                                              float* __restrict__ pred) {
  int g = blockIdx.x * 256 + threadIdx.x;
  int e = g >> 4;
  int l = g & 15;
  if (e >= NL) return;
  int i = eli[e], j = eli[NL + e];
  const float* zi = Z + (size_t)i * 256;
  const float* zj = Z + (size_t)j * 256 + 128;
  float s = 0.0f;
#pragma unroll
  for (int half = 0; half < 2; ++half) {
    int o = half * 64 + l * 4;
    float4 za = *(const float4*)(zi + o);
    float4 zb = *(const float4*)(zj + o);
    float4 bb = *(const float4*)(bl1 + o);
    float4 w2 = *(const float4*)(Wl2 + o);
    s += fmaxf(za.x + zb.x + bb.x, 0.f) * w2.x
       + fmaxf(za.y + zb.y + bb.y, 0.f) * w2.y
       + fmaxf(za.z + zb.z + bb.z, 0.f) * w2.z
       + fmaxf(za.w + zb.w + bb.w, 0.f) * w2.w;
  }
#pragma unroll
  for (int d = 1; d < 16; d <<= 1) s += __shfl_xor(s, d, 64);
  if (l == 0) pred[e] = s + bl2[0];
}

extern "C" void kernel_launch(void* const* d_in, const int* in_sizes, int n_in,
                              void* d_out, int out_size, void* d_ws, size_t ws_size,
                              hipStream_t stream) {
  const float* x   = (const float*)d_in[0];
  const float* W1  = (const float*)d_in[1];
  const float* b1  = (const float*)d_in[2];
  const float* Wl1 = (const float*)d_in[3];
  const float* bl1 = (const float*)d_in[4];
  const float* Wl2 = (const float*)d_in[5];
  const float* bl2 = (const float*)d_in[6];
  const int* ei    = (const int*)d_in[7];
  const int* eli   = (const int*)d_in[8];
  float* pred = (float*)d_out;

  char* ws = (char*)d_ws;
  size_t off = 0;
  auto alloc = [&](size_t bytes) {
    void* p = ws + off;
    off = (off + bytes + 255) & ~(size_t)255;
    return p;
  };
  float* dinv  = (float*)alloc(NN * 4);
  int* deg     = (int*)alloc(NN * 4);
  int* indeg   = (int*)alloc(NN * 4);
  int* colptr  = (int*)alloc((NN + 1) * 4);
  int* cursor  = (int*)alloc(NN * 4);
  int* bsum    = (int*)alloc(NB * 4);
  int* boff    = (int*)alloc(NB * 4);
  int* csrc    = (int*)alloc((size_t)NE * 4);
  float* WT1   = (float*)alloc(128 * 128 * 4);
  float* WTl1  = (float*)alloc(128 * 256 * 4);
  float* h     = (float*)alloc((size_t)NN * 128 * 4);
  float* hn    = (float*)alloc((size_t)NN * 128 * 4);  // contiguous after h
  float* hid   = (float*)alloc((size_t)NN * 128 * 4);
  float* Z     = h;  // 50000x256 f32 = 51.2MB overlays dead h+hn after agg

  k_init<<<NB, 256, 0, stream>>>(deg, indeg);
  k_count<<<(NE + 255) / 256, 256, 0, stream>>>(ei, deg, indeg);
  k_blocksum<<<NB, 256, 0, stream>>>(indeg, deg, dinv, bsum);
  k_scan_bsums<<<1, 256, 0, stream>>>(bsum, boff);
  k_colptr<<<NB, 256, 0, stream>>>(indeg, boff, colptr, cursor);
  k_fill<<<(NE + 255) / 256, 256, 0, stream>>>(ei, cursor, csrc);
  k_transW<<<192, 256, 0, stream>>>(W1, Wl1, WT1, WTl1);

  k_gemm2<128, 64, 1><<<(NN + 63) / 64, 256, 0, stream>>>(x, WT1, b1, h);

  k_agg<0><<<(NN * 32 + 255) / 256, 256, 0, stream>>>(h, hn, hid, dinv, colptr, csrc);
  k_agg<1><<<(NN * 32 + 255) / 256, 256, 0, stream>>>(hn, nullptr, hid, dinv, colptr, csrc);

  k_gemm2<256, 32, 0><<<(NN + 31) / 32, 256, 0, stream>>>(hid, WTl1, nullptr, Z);

  k_edge<<<(NL * 16 + 255) / 256, 256, 0, stream>>>(Z, bl1, Wl2, bl2, eli, pred);
}